// Round 9
// baseline (69.415 us; speedup 1.0000x reference)
//
#include <hip/hip_runtime.h>
#include <stdint.h>

// TopKLayer quirky sparse_hw: per row (3136 elems), t = spatial index of the
// k-th largest |x| (k=313, ties ascending index); keep the t smallest-|x|
// elements (stable). TWO ROWS PER BLOCK (256 thr): rows in registers, both
// rows processed between the same barriers (ILP 2), CDFs of both rows packed
// into ONE u16-paired wave scan, post-compaction select is wave-local
// (wave0->row0, wave1->row1, no barriers inside).

#define HW    3136
#define NW4   784        // HW/4
#define NT    256
#define KSEL  313u
#define CAP   320u       // candidate bin capacity (stat max ~190)
#define CAP2  64u        // tie-set capacity
#define O_CAND 0         // regions inside a row's s_h (dead after CDF)
#define O_HC   384
#define O_TINY 704
#define M31   0x7fffffffu
#define SENT  0xFFFFFFFFu

__device__ __forceinline__ unsigned wscan_incl(unsigned v) {
    const int lane = threadIdx.x & 63;
#pragma unroll
    for (int d = 1; d < 64; d <<= 1) {
        unsigned o = __shfl_up(v, d, 64);
        if (lane >= d) v += o;
    }
    return v;
}

__device__ __forceinline__ unsigned bcast_first(unsigned flag, unsigned val) {
    unsigned long long bal = __ballot(flag != 0);
    if (!bal) return 0u;
    return __shfl(val, __ffsll(bal) - 1, 64);
}

// One-wave finish: subhist over compacted candidates, locate, tie-rank.
// Reads br[1]=m1, br[3]=cnt. Writes br[2] UNCONDITIONALLY (SENT -> fallback).
template <bool fromTop>
__device__ void wave_finish(unsigned* hr, unsigned* br) {
    const int lane = threadIdx.x & 63;
    const unsigned cnt = br[3];
    const unsigned m1  = br[1];
    unsigned* cand = hr + O_CAND;
    unsigned* hc   = hr + O_HC;
    unsigned* tiny = hr + O_TINY;
    if (cnt > CAP) { if (lane == 0) br[2] = (m1 == 0) ? 0u : SENT; return; }
    for (unsigned i = lane; i < cnt; i += 64) atomicAdd(&hc[cand[i] >> 24], 1u);
    unsigned hh[4];
#pragma unroll
    for (int i = 0; i < 4; ++i) hh[i] = hc[4 * lane + i];
    const unsigned s4 = hh[0] + hh[1] + hh[2] + hh[3];
    unsigned run2 = wscan_incl(s4) - s4;
    unsigned packed2 = 0;
#pragma unroll
    for (int i = 0; i < 4; ++i) {
        if (fromTop) {
            const unsigned suf = cnt - run2 - hh[i];
            if (suf < m1 && m1 <= suf + hh[i])
                packed2 = ((unsigned)(4 * lane + i) << 16) | (m1 - suf);
        } else {
            if (run2 < m1 && m1 <= run2 + hh[i])
                packed2 = ((unsigned)(4 * lane + i) << 16) | (m1 - run2);
        }
        run2 += hh[i];
    }
    packed2 = bcast_first(packed2, packed2);
    if (packed2 == 0) { if (lane == 0) br[2] = 0u; return; }  // sentinel (m1==0)
    const unsigned b2 = packed2 >> 16;
    const unsigned m2 = packed2 & 0xFFFFu;
    // gather tie set (scan-based positions, order irrelevant)
    unsigned tc = 0;
    for (unsigned i = lane; i < cnt; i += 64) tc += ((cand[i] >> 24) == b2);
    const unsigned tincl = wscan_incl(tc);
    const unsigned c2 = __shfl((int)tincl, 63, 64);
    if (c2 > CAP2) { if (lane == 0) br[2] = SENT; return; }
    unsigned tpos = tincl - tc;
    for (unsigned i = lane; i < cnt; i += 64) {
        const unsigned cw = cand[i];
        if ((cw >> 24) == b2) tiny[tpos++] = cw;
    }
    unsigned hitf = 0, resv = 0;
    if ((unsigned)lane < c2) {
        const unsigned ci = tiny[lane];
        const unsigned di = fromTop ? (ci ^ 0xFFFu) : ci;
        unsigned r = 1;
        for (unsigned j = 0; j < c2; ++j) {
            const unsigned dj = fromTop ? (tiny[j] ^ 0xFFFu) : tiny[j];
            if (fromTop ? (dj > di) : (dj < di)) r++;
        }
        if (r == m2) { hitf = 1; resv = ci; }
    }
    resv = bcast_first(hitf, resv);
    if (lane == 0) br[2] = resv;
}

// Pathological fallback: bin-filtered counting rank over global row.
template <bool fromTop>
__device__ void block_fallback(const unsigned* __restrict__ gx, unsigned* br) {
    const unsigned b0 = br[0], m1 = br[1];
    const int t = threadIdx.x;
    for (int j = t; j < HW; j += NT) {
        const unsigned k = gx[j] & M31;
        if ((k >> 20) != b0) continue;
        unsigned Ci = ((k & 0xFFFFFu) << 12) | (unsigned)j;
        if (fromTop) Ci ^= 0xFFFu;
        unsigned r = 1;
        for (int j2 = 0; j2 < HW; ++j2) {
            const unsigned k2 = gx[j2] & M31;
            if ((k2 >> 20) != b0) continue;
            unsigned Cj = ((k2 & 0xFFFFFu) << 12) | (unsigned)j2;
            if (fromTop) Cj ^= 0xFFFu;
            if (fromTop ? (Cj > Ci) : (Cj < Ci)) r++;
        }
        if (r == m1) br[2] = ((k & 0xFFFFFu) << 12) | (unsigned)j;
    }
}

extern "C" __global__ void __launch_bounds__(NT)
topk_kernel(const float* __restrict__ x, float* __restrict__ out) {
    __shared__ unsigned s_h0[2048];   // row0 hist -> cand/hc/tiny reuse
    __shared__ unsigned s_h1[2048];   // row1
    __shared__ unsigned s_warp[4];
    __shared__ unsigned s_b0[4];      // [0]=bin [1]=m1 [2]=result [3]=counter
    __shared__ unsigned s_b1[4];

    const int t = threadIdx.x;
    const int lane = t & 63;
    const int wid = t >> 6;
    const size_t r0 = (size_t)blockIdx.x * 2;
    const uint4* __restrict__ xin0 = (const uint4*)(x + r0 * HW);
    const uint4* __restrict__ xin1 = (const uint4*)(x + (r0 + 1) * HW);
    uint4* __restrict__ xo0 = (uint4*)(out + r0 * HW);
    uint4* __restrict__ xo1 = (uint4*)(out + (r0 + 1) * HW);
    const unsigned* __restrict__ gx0 = (const unsigned*)xin0;
    const unsigned* __restrict__ gx1 = (const unsigned*)xin1;

    // P0: clear both histograms
    {
        const uint4 z = make_uint4(0u, 0u, 0u, 0u);
        ((uint4*)s_h0)[t] = z; ((uint4*)s_h0)[t + NT] = z;
        ((uint4*)s_h1)[t] = z; ((uint4*)s_h1)[t + NT] = z;
    }
    __syncthreads();

    // P1: load both rows into registers + 2048-bin hist (abs bits 30:20)
    const bool has3 = (t < NW4 - 3 * NT);   // t < 16
    uint4 va[4], vb[4];
#pragma unroll
    for (int i = 0; i < 3; ++i) { va[i] = xin0[t + i * NT]; vb[i] = xin1[t + i * NT]; }
    va[3] = has3 ? xin0[t + 3 * NT] : make_uint4(0u, 0u, 0u, 0u);
    vb[3] = has3 ? xin1[t + 3 * NT] : make_uint4(0u, 0u, 0u, 0u);
#pragma unroll
    for (int i = 0; i < 4; ++i) {
        if (i == 3 && !has3) break;
        atomicAdd(&s_h0[(va[i].x & M31) >> 20], 1u);
        atomicAdd(&s_h0[(va[i].y & M31) >> 20], 1u);
        atomicAdd(&s_h0[(va[i].z & M31) >> 20], 1u);
        atomicAdd(&s_h0[(va[i].w & M31) >> 20], 1u);
        atomicAdd(&s_h1[(vb[i].x & M31) >> 20], 1u);
        atomicAdd(&s_h1[(vb[i].y & M31) >> 20], 1u);
        atomicAdd(&s_h1[(vb[i].z & M31) >> 20], 1u);
        atomicAdd(&s_h1[(vb[i].w & M31) >> 20], 1u);
    }
    __syncthreads();

    // P2: packed CDF (row0 in low16, row1 in high16), ONE wave scan
    const uint4 ha = ((const uint4*)s_h0)[2 * t], hb = ((const uint4*)s_h0)[2 * t + 1];
    const uint4 hc = ((const uint4*)s_h1)[2 * t], hd = ((const uint4*)s_h1)[2 * t + 1];
    unsigned c01[8] = { ha.x | (hc.x << 16), ha.y | (hc.y << 16),
                        ha.z | (hc.z << 16), ha.w | (hc.w << 16),
                        hb.x | (hd.x << 16), hb.y | (hd.y << 16),
                        hb.z | (hd.z << 16), hb.w | (hd.w << 16) };
    unsigned ssum = 0;
#pragma unroll
    for (int i = 0; i < 8; ++i) ssum += c01[i];
    const unsigned Si = wscan_incl(ssum);
    if (lane == 63) s_warp[wid] = Si;
    __syncthreads();

    // P3: locate A for both rows (register CDF) + zero counters + clear hc
    unsigned cross = 0;
    for (int w2 = 0; w2 < wid; ++w2) cross += s_warp[w2];
    const unsigned base01 = cross + Si - ssum;   // excl CDF of bin 8t (packed)
    {
        unsigned run0 = base01 & 0xFFFFu, run1 = base01 >> 16;
#pragma unroll
        for (int i = 0; i < 8; ++i) {
            const unsigned c0 = c01[i] & 0xFFFFu, c1 = c01[i] >> 16;
            const unsigned suf0 = HW - run0 - c0;
            if (suf0 < KSEL && KSEL <= suf0 + c0) { s_b0[0] = 8u*(unsigned)t + (unsigned)i; s_b0[1] = KSEL - suf0; }
            const unsigned suf1 = HW - run1 - c1;
            if (suf1 < KSEL && KSEL <= suf1 + c1) { s_b1[0] = 8u*(unsigned)t + (unsigned)i; s_b1[1] = KSEL - suf1; }
            run0 += c0; run1 += c1;
        }
    }
    if (t == 0) { s_b0[3] = 0; s_b1[3] = 0; }
    s_h0[O_HC + t] = 0; s_h1[O_HC + t] = 0;
    __syncthreads();

    // P4: compact A, both rows, from registers
    auto compact = [&](const uint4* v, unsigned b0, unsigned* br, unsigned* cand) {
#pragma unroll
        for (int i = 0; i < 4; ++i) {
            if (i == 3 && !has3) break;
            const unsigned i0 = 4u * (unsigned)(t + i * NT);
            unsigned k, p;
            k = v[i].x & M31; if ((k >> 20) == b0) { p = atomicAdd(&br[3], 1u); if (p < CAP) cand[p] = ((k & 0xFFFFFu) << 12) | i0; }
            k = v[i].y & M31; if ((k >> 20) == b0) { p = atomicAdd(&br[3], 1u); if (p < CAP) cand[p] = ((k & 0xFFFFFu) << 12) | (i0 + 1u); }
            k = v[i].z & M31; if ((k >> 20) == b0) { p = atomicAdd(&br[3], 1u); if (p < CAP) cand[p] = ((k & 0xFFFFFu) << 12) | (i0 + 2u); }
            k = v[i].w & M31; if ((k >> 20) == b0) { p = atomicAdd(&br[3], 1u); if (p < CAP) cand[p] = ((k & 0xFFFFFu) << 12) | (i0 + 3u); }
        }
    };
    compact(va, s_b0[0], s_b0, s_h0 + O_CAND);
    compact(vb, s_b1[0], s_b1, s_h1 + O_CAND);
    __syncthreads();

    // P5: wave-local finish A (wave0 -> row0, wave1 -> row1)
    if (wid == 0) wave_finish<true>(s_h0, s_b0);
    else if (wid == 1) wave_finish<true>(s_h1, s_b1);
    __syncthreads();

    // P6: read tIdx; rare block fallback
    unsigned compA0 = s_b0[2], compA1 = s_b1[2];
    if (compA0 == SENT) { block_fallback<true>(gx0, s_b0); __syncthreads(); compA0 = s_b0[2]; }
    if (compA1 == SENT) { block_fallback<true>(gx1, s_b1); __syncthreads(); compA1 = s_b1[2]; }
    const unsigned tIdx0 = compA0 & 0xFFFu;
    const unsigned tIdx1 = compA1 & 0xFFFu;

    // P7 (same interval): locate B (register CDF) + zero counters + clear hc
    {
        unsigned run0 = base01 & 0xFFFFu, run1 = base01 >> 16;
#pragma unroll
        for (int i = 0; i < 8; ++i) {
            const unsigned c0 = c01[i] & 0xFFFFu, c1 = c01[i] >> 16;
            if (run0 < tIdx0 && tIdx0 <= run0 + c0) { s_b0[0] = 8u*(unsigned)t + (unsigned)i; s_b0[1] = tIdx0 - run0; }
            if (run1 < tIdx1 && tIdx1 <= run1 + c1) { s_b1[0] = 8u*(unsigned)t + (unsigned)i; s_b1[1] = tIdx1 - run1; }
            run0 += c0; run1 += c1;
        }
    }
    if (t == 0) {
        s_b0[3] = 0; s_b1[3] = 0;
        if (tIdx0 == 0) { s_b0[0] = 0; s_b0[1] = 0; }   // sentinel: keep nothing
        if (tIdx1 == 0) { s_b1[0] = 0; s_b1[1] = 0; }
    }
    s_h0[O_HC + t] = 0; s_h1[O_HC + t] = 0;
    __syncthreads();

    // P8: compact B, both rows
    const unsigned b0B0 = s_b0[0], b0B1 = s_b1[0];
    compact(va, b0B0, s_b0, s_h0 + O_CAND);
    compact(vb, b0B1, s_b1, s_h1 + O_CAND);
    __syncthreads();

    // P9: wave-local finish B
    if (wid == 0) wave_finish<false>(s_h0, s_b0);
    else if (wid == 1) wave_finish<false>(s_h1, s_b1);
    __syncthreads();

    unsigned compB0 = s_b0[2], compB1 = s_b1[2];
    if (compB0 == SENT) { block_fallback<false>(gx0, s_b0); __syncthreads(); compB0 = s_b0[2]; }
    if (compB1 == SENT) { block_fallback<false>(gx1, s_b1); __syncthreads(); compB1 = s_b1[2]; }
    const unsigned KB0 = (b0B0 << 20) | (compB0 >> 12);
    const unsigned eB0 = compB0 & 0xFFFu;
    const unsigned KB1 = (b0B1 << 20) | (compB1 >> 12);
    const unsigned eB1 = compB1 & 0xFFFu;

    // final: mask + store both rows from registers
    auto store_row = [&](const uint4* v, uint4* xo, unsigned KB, unsigned eB) {
#pragma unroll
        for (int i = 0; i < 4; ++i) {
            if (i == 3 && !has3) break;
            const unsigned i0 = 4u * (unsigned)(t + i * NT);
            uint4 o = v[i];
            unsigned k;
            k = o.x & M31; if (!(k < KB || (k == KB && i0      <= eB))) o.x = 0u;
            k = o.y & M31; if (!(k < KB || (k == KB && i0 + 1u <= eB))) o.y = 0u;
            k = o.z & M31; if (!(k < KB || (k == KB && i0 + 2u <= eB))) o.z = 0u;
            k = o.w & M31; if (!(k < KB || (k == KB && i0 + 3u <= eB))) o.w = 0u;
            xo[t + i * NT] = o;
        }
    };
    store_row(va, xo0, KB0, eB0);
    store_row(vb, xo1, KB1, eB1);
}

extern "C" void kernel_launch(void* const* d_in, const int* in_sizes, int n_in,
                              void* d_out, int out_size, void* d_ws, size_t ws_size,
                              hipStream_t stream) {
    const float* x = (const float*)d_in[0];
    float* out = (float*)d_out;
    const int rows = in_sizes[0] / HW;          // 8192
    topk_kernel<<<dim3(rows / 2), dim3(NT), 0, stream>>>(x, out);
}